// Round 5
// baseline (119.248 us; speedup 1.0000x reference)
//
#include <hip/hip_runtime.h>

// BlockLinear: y[r, c*3+o] = sum_i x[r, c*3+i] * W[c*9 + o*3 + i] + b[c*3+o]
// B=16384 rows, IN_FEATURES=3072 (=768 float4), C=1024 components (3x3 each).
//
// Memory-bound: 402 MB total, copy ceiling ~6.3 TB/s -> ~64 us floor.
//
// Round-5: copy-pattern global + IN-REGISTER repack ("expanded weights").
//   - Lane owns float4 [d0..d0+3] of a row (lane <-> float4 contiguous, the
//     exact D2D-copy access pattern for both load and store).
//   - Output dword d0+j belongs to component (d0+j)/3 with output idx
//     o=(d0+j)%3; its 3 inputs live in window positions [j-2..j+2] around the
//     lane's float4. Expanded weights G[j][5] (zeros outside the component)
//     are precomputed once -> y_j = b_j + sum_dp G[j][dp]*win[j+dp].
//   - Window edges (2 dwords either side) come from neighbor lanes via
//     __shfl; wave-boundary lanes (0 / 63) patch with an 8B global load.
//   - No LDS round-trip, no barriers, no waitcnt fences: R3 failed on block
//     lockstep, R4 on the serialized LDS chain. Here waves are fully
//     decoupled and the compiler can pipeline row iterations freely.

#define NROWS  16384
#define ROWD   3072       // dwords per row
#define ROW4   768        // float4 per row
#define CHUNKS 12         // 256-dword chunks per row (one chunk per wave)
#define RPW    8          // rows per wave

__global__ __launch_bounds__(256)
void block_linear_kernel(const float* __restrict__ x,
                         const float* __restrict__ W,
                         const float* __restrict__ bias,
                         float* __restrict__ out) {
    const int tid = blockIdx.x * blockDim.x + threadIdx.x;
    const int l   = tid & 63;          // lane
    const int gw  = tid >> 6;          // global wave id, 0..24575
    const int cc  = gw % CHUNKS;       // 256-dword chunk within row (fixed)
    const int rg  = gw / CHUNKS;       // row group, 0..2047

    const int d0 = cc * 256 + 4 * l;   // this lane's column dword (fixed)

    // ---- init: expanded weights G[j][dp+2] and bias, once per lane ----
    float G[4][5];
    float bb[4];
    #pragma unroll
    for (int j = 0; j < 4; ++j) {
        const int dcol = d0 + j;           // column dword of output j
        const int comp = dcol / 3;
        const int o    = dcol % 3;
        bb[j] = bias[comp * 3 + o];
        #pragma unroll
        for (int dp = -2; dp <= 2; ++dp) {
            const int t = dp + o;          // index into the 3-input dot
            G[j][dp + 2] = (t >= 0 && t < 3) ? W[comp * 9 + o * 3 + t] : 0.0f;
        }
    }

    // Wave-edge patches: lane 0 may need 2 dwords before the chunk,
    // lane 63 may need 2 after (component straddles the chunk boundary
    // unless the boundary is component-aligned).
    const bool need_pre = (l == 0)  && (cc % 3 != 0);
    const bool need_nxt = (l == 63) && (cc % 3 != 2);  // cc=11 has %3==2: row end is comp-aligned

    const float4* x4   = reinterpret_cast<const float4*>(x);
    float4*       out4 = reinterpret_cast<float4*>(out);

    #pragma unroll 2
    for (int k = 0; k < RPW; ++k) {
        const int row = rg * RPW + k;
        const size_t base4 = (size_t)row * ROW4 + (size_t)cc * 64 + l;
        const size_t baseD = (size_t)row * ROWD + (size_t)cc * 256;

        float4 v = x4[base4];

        float2 pre = make_float2(0.f, 0.f), nxt = make_float2(0.f, 0.f);
        if (need_pre) pre = *reinterpret_cast<const float2*>(x + baseD - 2);
        if (need_nxt) nxt = *reinterpret_cast<const float2*>(x + baseD + 256);

        // neighbor dwords via shuffle (rotation; wrapped lanes overridden)
        float wm2 = __shfl(v.z, l - 1);
        float wm1 = __shfl(v.w, l - 1);
        float wp4 = __shfl(v.x, l + 1);
        float wp5 = __shfl(v.y, l + 1);
        if (l == 0)  { wm2 = pre.x; wm1 = pre.y; }
        if (l == 63) { wp4 = nxt.x; wp5 = nxt.y; }

        const float win[8] = { wm2, wm1, v.x, v.y, v.z, v.w, wp4, wp5 };

        float y[4];
        #pragma unroll
        for (int j = 0; j < 4; ++j) {
            float acc = bb[j];
            #pragma unroll
            for (int dp = -2; dp <= 2; ++dp)
                acc = fmaf(G[j][dp + 2], win[j + dp + 2], acc);
            y[j] = acc;
        }

        float4 yo = { y[0], y[1], y[2], y[3] };
        out4[base4] = yo;
    }
}

extern "C" void kernel_launch(void* const* d_in, const int* in_sizes, int n_in,
                              void* d_out, int out_size, void* d_ws, size_t ws_size,
                              hipStream_t stream) {
    const float* x = (const float*)d_in[0];
    const float* W = (const float*)d_in[1];
    const float* b = (const float*)d_in[2];
    float* out = (float*)d_out;

    const int total_waves = CHUNKS * (NROWS / RPW);   // 24576
    const int block = 256;                            // 4 waves
    const int grid  = total_waves / 4;                // 6144
    block_linear_kernel<<<grid, block, 0, stream>>>(x, W, b, out);
}

// Round 6
// 73.612 us; speedup vs baseline: 1.6200x; 1.6200x over previous
//
#include <hip/hip_runtime.h>

// BlockLinear: y[r, c*3+o] = sum_i x[r, c*3+i] * W[c*9 + o*3 + i] + b[c*3+o]
// B=16384 rows, IN_FEATURES=3072, C=1024 components (3x3 Linear each).
//
// Memory-bound streaming, ~402 MB logical traffic; L3 (256MB) serves ~half
// of x's reads -> HBM ~296 MB. R1 (74.1 us) was latency-bound, not BW-bound:
// serial per-row load->fma->store chain left ~2 loads in flight per wave.
//
// Round-6 = Round-1 mapping (thread owns component c, wave = 768B contiguous
// dwordx3, the only structure that hasn't lost to repack overhead) + ONE
// change: batch all 8 row-loads up front so 8 independent dwordx3 loads are
// in flight per lane (6 KB/wave) before any use. Compiler inserts per-use
// vmcnt(N) waits -> compute on row k overlaps loads of rows k+1..7.

#define NROWS      16384
#define INF        3072
#define NCOMP      1024
#define ROWS_PER_T 8

struct f3 { float a, b, c; };  // 12-byte chunk, 4B-aligned

__global__ __launch_bounds__(256)
void block_linear_kernel(const float* __restrict__ x,
                         const float* __restrict__ W,
                         const float* __restrict__ bias,
                         float* __restrict__ out) {
    const int tid = blockIdx.x * blockDim.x + threadIdx.x;
    const int c   = tid & (NCOMP - 1);   // component; consecutive lanes -> consecutive c
    const int rg  = tid >> 10;           // row group

    // Weights/bias for this component, loaded once (L2-resident, 48 KB total).
    const float* w = W + c * 9;
    const float w00 = w[0], w01 = w[1], w02 = w[2];
    const float w10 = w[3], w11 = w[4], w12 = w[5];
    const float w20 = w[6], w21 = w[7], w22 = w[8];
    const float* bp = bias + c * 3;
    const float b0 = bp[0], b1 = bp[1], b2 = bp[2];

    const int r0 = rg * ROWS_PER_T;
    const size_t colb = (size_t)c * 3;

    // Phase 1: issue all 8 independent row loads (no uses in between).
    f3 v[ROWS_PER_T];
    #pragma unroll
    for (int k = 0; k < ROWS_PER_T; ++k)
        v[k] = *reinterpret_cast<const f3*>(x + (size_t)(r0 + k) * INF + colb);

    // Phase 2: compute + store per row; store of row k overlaps the
    // still-outstanding loads of later rows (compiler waits vmcnt(7-k)).
    #pragma unroll
    for (int k = 0; k < ROWS_PER_T; ++k) {
        f3 y;
        y.a = fmaf(w00, v[k].a, fmaf(w01, v[k].b, fmaf(w02, v[k].c, b0)));
        y.b = fmaf(w10, v[k].a, fmaf(w11, v[k].b, fmaf(w12, v[k].c, b1)));
        y.c = fmaf(w20, v[k].a, fmaf(w21, v[k].b, fmaf(w22, v[k].c, b2)));
        *reinterpret_cast<f3*>(out + (size_t)(r0 + k) * INF + colb) = y;
    }
}

extern "C" void kernel_launch(void* const* d_in, const int* in_sizes, int n_in,
                              void* d_out, int out_size, void* d_ws, size_t ws_size,
                              hipStream_t stream) {
    const float* x = (const float*)d_in[0];
    const float* W = (const float*)d_in[1];
    const float* b = (const float*)d_in[2];
    float* out = (float*)d_out;

    const int total_threads = (NROWS / ROWS_PER_T) * NCOMP;  // 2,097,152
    const int block = 256;
    const int grid = total_threads / block;                  // 8192
    block_linear_kernel<<<grid, block, 0, stream>>>(x, W, b, out);
}

// Round 7
// 62.016 us; speedup vs baseline: 1.9229x; 1.1870x over previous
//
#include <hip/hip_runtime.h>

// BlockLinear: y[r, c*3+o] = sum_i x[r, c*3+i] * W[c*9 + o*3 + i] + b[c*3+o]
// B=16384 rows, IN_FEATURES=3072, C=1024 components (3x3 Linear each).
//
// R1/R6 (73.6-74.1 us) = contiguous dwordx3 streaming at ~5.5 TB/s total,
// 87% of the copy mix; NOT latency-bound (explicit batching was neutral).
// Counter evidence: FETCH ~101 MB (L3 serves half of x), WRITE ~201 MB all
// the way to HBM. x (192 MiB) would fit L3 (256 MiB) if out's streaming
// stores didn't allocate/evict.
//
// Round-7 = R6 + ONE change: non-temporal stores (nt bit -> no-allocate /
// evict-first) so out stops polluting L3, x goes ~fully L3-resident across
// the timed replays, and HBM traffic drops ~302 -> ~201 MB per call.
// Store is 3 nt dwords (12B chunk can't be one nt vector: float3 pads to
// 16B, float2 misaligns for odd c); same-wave dword stores merge to full
// lines in L2 write buffers, VMEM issue rate is nowhere near a limit.

#define NROWS      16384
#define INF        3072
#define NCOMP      1024
#define ROWS_PER_T 8

struct f3 { float a, b, c; };  // 12-byte chunk, 4B-aligned

__global__ __launch_bounds__(256)
void block_linear_kernel(const float* __restrict__ x,
                         const float* __restrict__ W,
                         const float* __restrict__ bias,
                         float* __restrict__ out) {
    const int tid = blockIdx.x * blockDim.x + threadIdx.x;
    const int c   = tid & (NCOMP - 1);   // component; consecutive lanes -> consecutive c
    const int rg  = tid >> 10;           // row group

    // Weights/bias for this component, loaded once (48 KB total, L2-resident).
    const float* w = W + c * 9;
    const float w00 = w[0], w01 = w[1], w02 = w[2];
    const float w10 = w[3], w11 = w[4], w12 = w[5];
    const float w20 = w[6], w21 = w[7], w22 = w[8];
    const float* bp = bias + c * 3;
    const float b0 = bp[0], b1 = bp[1], b2 = bp[2];

    const int r0 = rg * ROWS_PER_T;
    const size_t colb = (size_t)c * 3;

    // Phase 1: issue all 8 independent row loads (normal, cacheable -> L3).
    f3 v[ROWS_PER_T];
    #pragma unroll
    for (int k = 0; k < ROWS_PER_T; ++k)
        v[k] = *reinterpret_cast<const f3*>(x + (size_t)(r0 + k) * INF + colb);

    // Phase 2: compute + non-temporal store per row.
    #pragma unroll
    for (int k = 0; k < ROWS_PER_T; ++k) {
        float ya = fmaf(w00, v[k].a, fmaf(w01, v[k].b, fmaf(w02, v[k].c, b0)));
        float yb = fmaf(w10, v[k].a, fmaf(w11, v[k].b, fmaf(w12, v[k].c, b1)));
        float yc = fmaf(w20, v[k].a, fmaf(w21, v[k].b, fmaf(w22, v[k].c, b2)));
        float* o = out + (size_t)(r0 + k) * INF + colb;
        __builtin_nontemporal_store(ya, o + 0);
        __builtin_nontemporal_store(yb, o + 1);
        __builtin_nontemporal_store(yc, o + 2);
    }
}

extern "C" void kernel_launch(void* const* d_in, const int* in_sizes, int n_in,
                              void* d_out, int out_size, void* d_ws, size_t ws_size,
                              hipStream_t stream) {
    const float* x = (const float*)d_in[0];
    const float* W = (const float*)d_in[1];
    const float* b = (const float*)d_in[2];
    float* out = (float*)d_out;

    const int total_threads = (NROWS / ROWS_PER_T) * NCOMP;  // 2,097,152
    const int block = 256;
    const int grid = total_threads / block;                  // 8192
    block_linear_kernel<<<grid, block, 0, stream>>>(x, W, b, out);
}